// Round 1
// baseline (811.399 us; speedup 1.0000x reference)
//
#include <hip/hip_runtime.h>
#include <math.h>

#define Hd 264
#define Wd 480
#define HW (Hd * Wd)
#define NB 16
#define NC 9
#define KK 50
#define NPLANE (NB * NC)
#define NDET (NB * KK)
#define CAP 6912
#define PI_F 3.14159274101257324f
#define TWO_PI_F 6.28318548202514648f

__device__ const float DIMM[9][3] = {
    {3.99331126f, 1.54370861f, 1.64175497f},
    {0.295f, 1.6f, 0.3175f},
    {1.34645161f, 1.55322581f, 0.3883871f},
    {2.503f, 1.72f, 1.077f},
    {9.1775f, 2.95f, 2.3425f},
    {10.3655102f, 3.31632653f, 2.45469388f},
    {6.016911083f, 3.412001685f, 2.2783185f},
    {4.824963f, 2.046904f, 1.78939f},
    {8.8040879f, 2.916193f, 2.07649252f}};

__device__ const float ACENT[4] = {0.0f, 1.57079637050628662f, 3.14159274101257324f, -1.57079637050628662f};

// Kernel 1: per (b,c) plane — fused 5x5 NMS + survivor compaction + exact top-50.
// Key = (value_bits << 32) | ~idx  (heat >= 0, so float-bit order == value order;
// ~idx gives jax.lax.top_k's lower-index-wins tiebreak).
__global__ __launch_bounds__(256) void nms_topk_plane(const float* __restrict__ cls,
                                                      unsigned long long* __restrict__ planeKeys) {
    __shared__ unsigned long long cand[CAP];
    __shared__ int cnt;
    __shared__ unsigned long long redk[256];
    __shared__ int redp[256];

    const int tid = threadIdx.x;
    const float* heat = cls + (size_t)blockIdx.x * HW;
    if (tid == 0) cnt = 0;
    __syncthreads();

    // Separable NMS over 8-pixel runs: 12 column-maxes (5-tap vertical) per run.
    const int RUNS = Hd * (Wd / 8);  // 264 * 60
    for (int r = tid; r < RUNS; r += 256) {
        const int y = r / 60;
        const int x0 = (r - y * 60) * 8;
        const int ylo = max(y - 2, 0), yhi = min(y + 2, Hd - 1);
        float cm[12];
#pragma unroll
        for (int dx = 0; dx < 12; ++dx) {
            const int x = x0 + dx - 2;
            float m = -INFINITY;
            if (x >= 0 && x < Wd) {
                for (int yy = ylo; yy <= yhi; ++yy) m = fmaxf(m, heat[yy * Wd + x]);
            }
            cm[dx] = m;
        }
#pragma unroll
        for (int i = 0; i < 8; ++i) {
            const int x = x0 + i;
            const float v = heat[y * Wd + x];
            const float hm = fmaxf(fmaxf(fmaxf(cm[i], cm[i + 1]), fmaxf(cm[i + 2], cm[i + 3])), cm[i + 4]);
            if (v == hm) {  // local max survives (non-strict, matches hmax==heat)
                const int pos = atomicAdd(&cnt, 1);
                if (pos < CAP) {
                    const unsigned int idx = (unsigned int)(y * Wd + x);
                    cand[pos] = ((unsigned long long)__float_as_uint(v) << 32) |
                                (unsigned long long)(0xFFFFFFFFu - idx);
                }
            }
        }
    }
    __syncthreads();
    const int n = min(cnt, CAP);

    // 50 rounds of block-wide argmax over candidates; winner removed each round.
    for (int it = 0; it < KK; ++it) {
        unsigned long long mk = 0;
        int mp = -1;
        for (int j = tid; j < n; j += 256) {
            const unsigned long long k = cand[j];
            if (k > mk) { mk = k; mp = j; }
        }
        redk[tid] = mk;
        redp[tid] = mp;
        __syncthreads();
        for (int s = 128; s > 0; s >>= 1) {
            if (tid < s) {
                if (redk[tid + s] > redk[tid]) { redk[tid] = redk[tid + s]; redp[tid] = redp[tid + s]; }
            }
            __syncthreads();
        }
        if (tid == 0) {
            planeKeys[blockIdx.x * KK + it] = redk[0];
            if (redp[0] >= 0) cand[redp[0]] = 0;
        }
        __syncthreads();
    }
}

// Kernel 2: per batch — top-50 over the 450 (class,rank) candidates.
// Tiebreak: lower flat index (class-major) wins, matching top_k on the reshaped array.
__global__ __launch_bounds__(256) void batch_topk(const unsigned long long* __restrict__ planeKeys,
                                                  float* __restrict__ dScore, int* __restrict__ dInd,
                                                  int* __restrict__ dCls) {
    __shared__ unsigned long long k2[NC * KK];
    __shared__ unsigned int sidx[NC * KK];
    __shared__ unsigned long long redk[256];
    __shared__ int redp[256];

    const int b = blockIdx.x;
    const int tid = threadIdx.x;
    for (int j = tid; j < NC * KK; j += 256) {
        const unsigned long long pk = planeKeys[(b * NC + j / KK) * KK + (j % KK)];
        sidx[j] = 0xFFFFFFFFu - (unsigned int)(pk & 0xFFFFFFFFull);
        k2[j] = (pk & 0xFFFFFFFF00000000ull) | (unsigned long long)(0xFFFFFFFFu - (unsigned int)j);
    }
    __syncthreads();

    for (int it = 0; it < KK; ++it) {
        unsigned long long mk = 0;
        int mp = -1;
        for (int j = tid; j < NC * KK; j += 256) {
            if (k2[j] > mk) { mk = k2[j]; mp = j; }
        }
        redk[tid] = mk;
        redp[tid] = mp;
        __syncthreads();
        for (int s = 128; s > 0; s >>= 1) {
            if (tid < s) {
                if (redk[tid + s] > redk[tid]) { redk[tid] = redk[tid + s]; redp[tid] = redp[tid + s]; }
            }
            __syncthreads();
        }
        if (tid == 0) {
            const int f = redp[0];
            dScore[b * KK + it] = __uint_as_float((unsigned int)(redk[0] >> 32));
            dInd[b * KK + it] = (int)sidx[f];
            dCls[b * KK + it] = f / KK;
            k2[f] = 0;
        }
        __syncthreads();
    }
}

// Kernel 3: single block — gather regs, batch-global segment-max dedup, per-det math.
__global__ __launch_bounds__(1024) void finalize_dets(const float* __restrict__ regs,
                                                      const float* __restrict__ calib,
                                                      const float* __restrict__ dScore,
                                                      const int* __restrict__ dInd,
                                                      const int* __restrict__ dCls,
                                                      float* __restrict__ out) {
    __shared__ int s_ind[NDET];
    __shared__ float s_key[NDET];

    const int i = threadIdx.x;
    float score = 0.0f, keyv = -INFINITY;
    int ind = 0, cls = 0;
    bool th = false;
    if (i < NDET) {
        score = dScore[i];
        ind = dInd[i];
        cls = dCls[i];
        th = score >= 0.29f;
        keyv = th ? (float)cls * 10000.0f - (float)i : -INFINITY;
        s_ind[i] = ind;
        s_key[i] = keyv;
    }
    __syncthreads();
    if (i >= NDET) return;

    // segment_max over spatial index, shared across ALL batches (reference semantics)
    float m = -INFINITY;
    for (int j = 0; j < NDET; ++j) {
        if (s_ind[j] == ind) m = fmaxf(m, s_key[j]);
    }
    const bool valid = th && (keyv == m);

    const int b = i / KK;
    const float x = (float)(ind % Wd);
    const float y = (float)(ind / Wd);
    const float* rp = regs + (size_t)b * 46 * HW + (size_t)ind;

    const float r0 = fmaxf(rp[0 * HW], 0.0f);
    const float r1 = fmaxf(rp[1 * HW], 0.0f);
    const float r2 = fmaxf(rp[2 * HW], 0.0f);
    const float r3 = fmaxf(rp[3 * HW], 0.0f);
    const float cx = x + rp[4 * HW];
    const float cy = y + rp[5 * HW];
    const float d0 = rp[22 * HW], d1 = rp[23 * HW], d2 = rp[24 * HW];
    float ori[16];
#pragma unroll
    for (int t = 0; t < 16; ++t) ori[t] = rp[(25 + t) * HW];
    const float dep_off = rp[41 * HW];

    const float bx1 = fminf(fmaxf((cx - r0) * 4.0f, 0.0f), 1920.0f);
    const float by1 = fminf(fmaxf((cy - r1) * 4.0f, 0.0f), 1056.0f);
    const float bx2 = fminf(fmaxf((cx + r2) * 4.0f, 0.0f), 1920.0f);
    const float by2 = fminf(fmaxf((cy + r3) * 4.0f, 0.0f), 1056.0f);

    const float dim0 = expf(d0) * DIMM[cls][0];
    const float dim1 = expf(d1) * DIMM[cls][1];
    const float dim2 = expf(d2) * DIMM[cls][2];

    const float sig = 1.0f / (1.0f + expf(-dep_off));
    const float depth = fminf(fmaxf(1.0f / sig - 1.0f, 0.1f), 200.0f);

    const float fu = calib[0], cu = calib[2], fv = calib[5], cv = calib[6];
    const float bxo = calib[3] / -fu;
    const float byo = calib[7] / -fv;
    const float pix = cx * 4.0f, piy = cy * 4.0f;
    const float locx = (pix - cu) * depth / fu + bxo;
    const float locy = (piy - cv) * depth / fv + byo;

    // bin argmax via 2-way softmax prob of class 1 (first-max tiebreak like jnp.argmax)
    float best = -INFINITY;
    int bidx = 0;
#pragma unroll
    for (int t = 0; t < 4; ++t) {
        const float l0 = ori[2 * t], l1 = ori[2 * t + 1];
        const float mm = fmaxf(l0, l1);
        const float p1 = expf(l1 - mm) / (expf(l0 - mm) + expf(l1 - mm));
        if (p1 > best) { best = p1; bidx = t; }
    }
    const float sel0 = ori[8 + 2 * bidx], sel1 = ori[8 + 2 * bidx + 1];
    float alpha = atanf(sel0 / sel1) + ACENT[bidx];
    const float ray = atanf(locx / depth);
    float roty = alpha + ray;
    if (roty > PI_F) roty -= TWO_PI_F;
    if (roty < -PI_F) roty += TWO_PI_F;
    if (alpha > PI_F) alpha -= TWO_PI_F;
    if (alpha < -PI_F) alpha += TWO_PI_F;

    float* o = out + (size_t)i * 14;
    o[0] = bx1; o[1] = by1; o[2] = bx2; o[3] = by2;
    o[4] = dim0; o[5] = dim1; o[6] = dim2;
    o[7] = depth;
    o[8] = locx; o[9] = locy; o[10] = depth;
    o[11] = roty; o[12] = alpha;
    o[13] = score;
    out[NDET * 14 + i] = valid ? 1.0f : 0.0f;
    out[NDET * 15 + i] = (float)cls;
}

extern "C" void kernel_launch(void* const* d_in, const int* in_sizes, int n_in,
                              void* d_out, int out_size, void* d_ws, size_t ws_size,
                              hipStream_t stream) {
    const float* cls = (const float*)d_in[0];
    const float* regs = (const float*)d_in[1];
    const float* calib = (const float*)d_in[2];
    float* out = (float*)d_out;
    char* ws = (char*)d_ws;

    unsigned long long* planeKeys = (unsigned long long*)ws;          // 144*50*8 = 57600 B
    float* dScore = (float*)(ws + 57600);                             // 800*4
    int* dInd = (int*)(ws + 60800);                                   // 800*4
    int* dCls = (int*)(ws + 64000);                                   // 800*4

    hipLaunchKernelGGL(nms_topk_plane, dim3(NPLANE), dim3(256), 0, stream, cls, planeKeys);
    hipLaunchKernelGGL(batch_topk, dim3(NB), dim3(256), 0, stream, planeKeys, dScore, dInd, dCls);
    hipLaunchKernelGGL(finalize_dets, dim3(1), dim3(1024), 0, stream, regs, calib, dScore, dInd, dCls, out);
}

// Round 2
// 337.514 us; speedup vs baseline: 2.4040x; 2.4040x over previous
//
#include <hip/hip_runtime.h>
#include <math.h>

#define Hd 264
#define Wd 480
#define HW (Hd * Wd)
#define NB 16
#define NC 9
#define KK 50
#define NPLANE (NB * NC)
#define NDET (NB * KK)
#define CAP 6912
#define ROWS 8
#define CHUNKS (Hd / ROWS)  // 33
#define LOCCAP 1024
#define PI_F 3.14159274101257324f
#define TWO_PI_F 6.28318548202514648f

__device__ const float DIMM[9][3] = {
    {3.99331126f, 1.54370861f, 1.64175497f},
    {0.295f, 1.6f, 0.3175f},
    {1.34645161f, 1.55322581f, 0.3883871f},
    {2.503f, 1.72f, 1.077f},
    {9.1775f, 2.95f, 2.3425f},
    {10.3655102f, 3.31632653f, 2.45469388f},
    {6.016911083f, 3.412001685f, 2.2783185f},
    {4.824963f, 2.046904f, 1.78939f},
    {8.8040879f, 2.916193f, 2.07649252f}};

__device__ const float ACENT[4] = {0.0f, 1.57079637050628662f, 3.14159274101257324f, -1.57079637050628662f};

// Kernel 1: NMS over an 8-row stripe of one (b,c) plane; survivors appended to a
// per-plane global list. Key = (value_bits << 32) | ~idx — unique per pixel, so
// list order (atomics) doesn't affect later keyed selection.
__global__ __launch_bounds__(256) void nms_compact(const float* __restrict__ cls,
                                                   unsigned long long* __restrict__ planeList,
                                                   int* __restrict__ planeCnt) {
    __shared__ float srows[(ROWS + 4) * Wd];  // 23 KB
    __shared__ float scol[ROWS * Wd];         // 15.4 KB
    __shared__ unsigned long long sbuf[LOCCAP];
    __shared__ int scnt, sbase;

    const int plane = blockIdx.y;
    const int chunk = blockIdx.x;
    const int tid = threadIdx.x;
    const float* heat = cls + (size_t)plane * HW;
    const int y0 = chunk * ROWS;

    if (tid == 0) scnt = 0;

    // Stage rows y0-2 .. y0+ROWS+1 (clamped to -inf outside) — coalesced.
    for (int j = tid; j < (ROWS + 4) * Wd; j += 256) {
        const int ry = y0 - 2 + j / Wd;
        const int x = j - (j / Wd) * Wd;
        srows[j] = (ry >= 0 && ry < Hd) ? heat[ry * Wd + x] : -INFINITY;
    }
    __syncthreads();

    // Vertical 5-tap max.
    for (int j = tid; j < ROWS * Wd; j += 256) {
        float m = fmaxf(fmaxf(srows[j], srows[j + Wd]), fmaxf(srows[j + 2 * Wd], srows[j + 3 * Wd]));
        scol[j] = fmaxf(m, srows[j + 4 * Wd]);
    }
    __syncthreads();

    // Horizontal 5-tap max + survivor detection.
    for (int j = tid; j < ROWS * Wd; j += 256) {
        const int r = j / Wd;
        const int x = j - r * Wd;
        float hm = scol[j];
        if (x >= 1) hm = fmaxf(hm, scol[j - 1]);
        if (x >= 2) hm = fmaxf(hm, scol[j - 2]);
        if (x <= Wd - 2) hm = fmaxf(hm, scol[j + 1]);
        if (x <= Wd - 3) hm = fmaxf(hm, scol[j + 2]);
        const float v = srows[(r + 2) * Wd + x];
        if (v == hm) {
            const unsigned int idx = (unsigned int)((y0 + r) * Wd + x);
            const unsigned long long key =
                ((unsigned long long)__float_as_uint(v) << 32) | (unsigned long long)(0xFFFFFFFFu - idx);
            const int p = atomicAdd(&scnt, 1);
            if (p < LOCCAP) {
                sbuf[p] = key;
            } else {  // pathological overflow: direct global append
                const int g = atomicAdd(&planeCnt[plane], 1);
                if (g < CAP) planeList[(size_t)plane * CAP + g] = key;
            }
        }
    }
    __syncthreads();
    const int nloc = min(scnt, LOCCAP);
    if (tid == 0) sbase = atomicAdd(&planeCnt[plane], nloc);
    __syncthreads();
    const int base = sbase;
    for (int j = tid; j < nloc; j += 256) {
        const int g = base + j;
        if (g < CAP) planeList[(size_t)plane * CAP + g] = sbuf[j];
    }
}

// Kernel 2: per-plane exact top-50 over the candidate list. Remove-by-key +
// wave-shfl reduction (2 barriers/round).
__global__ __launch_bounds__(256) void plane_topk(const unsigned long long* __restrict__ planeList,
                                                  const int* __restrict__ planeCnt,
                                                  unsigned long long* __restrict__ planeKeys) {
    __shared__ unsigned long long cand[CAP];
    __shared__ unsigned long long wmax[4];
    __shared__ unsigned long long sprev;

    const int plane = blockIdx.x;
    const int tid = threadIdx.x;
    const int n = min(planeCnt[plane], CAP);
    const unsigned long long* src = planeList + (size_t)plane * CAP;
    for (int j = tid; j < n; j += 256) cand[j] = src[j];
    __syncthreads();

    unsigned long long prev = ~0ull;  // > any real key (value < 1.0)
    for (int it = 0; it < KK; ++it) {
        unsigned long long mk = 0;
        for (int j = tid; j < n; j += 256) {
            unsigned long long k = cand[j];
            if (k == prev) { cand[j] = 0; k = 0; }
            if (k > mk) mk = k;
        }
        for (int s = 32; s > 0; s >>= 1) {
            const unsigned long long o = __shfl_down(mk, s);
            if (o > mk) mk = o;
        }
        if ((tid & 63) == 0) wmax[tid >> 6] = mk;
        __syncthreads();
        if (tid == 0) {
            unsigned long long m = wmax[0];
            if (wmax[1] > m) m = wmax[1];
            if (wmax[2] > m) m = wmax[2];
            if (wmax[3] > m) m = wmax[3];
            planeKeys[plane * KK + it] = m;
            sprev = m;
        }
        __syncthreads();
        prev = sprev;
    }
}

// Kernel 3: per batch — top-50 over 450 (class,rank) candidates; lower
// class-major flat index wins ties (matches top_k on reshaped array).
__global__ __launch_bounds__(256) void batch_topk(const unsigned long long* __restrict__ planeKeys,
                                                  float* __restrict__ dScore, int* __restrict__ dInd,
                                                  int* __restrict__ dCls) {
    __shared__ unsigned long long k2[NC * KK];
    __shared__ unsigned int sidx[NC * KK];
    __shared__ unsigned long long wmax[4];
    __shared__ unsigned long long sprev;

    const int b = blockIdx.x;
    const int tid = threadIdx.x;
    for (int j = tid; j < NC * KK; j += 256) {
        const unsigned long long pk = planeKeys[(b * NC + j / KK) * KK + (j % KK)];
        sidx[j] = 0xFFFFFFFFu - (unsigned int)(pk & 0xFFFFFFFFull);
        k2[j] = (pk & 0xFFFFFFFF00000000ull) | (unsigned long long)(0xFFFFFFFFu - (unsigned int)j);
    }
    __syncthreads();

    unsigned long long prev = ~0ull;
    for (int it = 0; it < KK; ++it) {
        unsigned long long mk = 0;
        for (int j = tid; j < NC * KK; j += 256) {
            unsigned long long k = k2[j];
            if (k == prev) { k2[j] = 0; k = 0; }
            if (k > mk) mk = k;
        }
        for (int s = 32; s > 0; s >>= 1) {
            const unsigned long long o = __shfl_down(mk, s);
            if (o > mk) mk = o;
        }
        if ((tid & 63) == 0) wmax[tid >> 6] = mk;
        __syncthreads();
        if (tid == 0) {
            unsigned long long m = wmax[0];
            if (wmax[1] > m) m = wmax[1];
            if (wmax[2] > m) m = wmax[2];
            if (wmax[3] > m) m = wmax[3];
            const int f = (int)(0xFFFFFFFFu - (unsigned int)(m & 0xFFFFFFFFull));
            dScore[b * KK + it] = __uint_as_float((unsigned int)(m >> 32));
            dInd[b * KK + it] = (int)sidx[f];
            dCls[b * KK + it] = f / KK;
            sprev = m;
        }
        __syncthreads();
        prev = sprev;
    }
}

// Kernel 4: single block — gather regs, batch-global segment-max dedup, per-det math.
__global__ __launch_bounds__(1024) void finalize_dets(const float* __restrict__ regs,
                                                      const float* __restrict__ calib,
                                                      const float* __restrict__ dScore,
                                                      const int* __restrict__ dInd,
                                                      const int* __restrict__ dCls,
                                                      float* __restrict__ out) {
    __shared__ int s_ind[NDET];
    __shared__ float s_key[NDET];

    const int i = threadIdx.x;
    float score = 0.0f, keyv = -INFINITY;
    int ind = 0, cls = 0;
    bool th = false;
    if (i < NDET) {
        score = dScore[i];
        ind = dInd[i];
        cls = dCls[i];
        th = score >= 0.29f;
        keyv = th ? (float)cls * 10000.0f - (float)i : -INFINITY;
        s_ind[i] = ind;
        s_key[i] = keyv;
    }
    __syncthreads();
    if (i >= NDET) return;

    float m = -INFINITY;
    for (int j = 0; j < NDET; ++j) {
        if (s_ind[j] == ind) m = fmaxf(m, s_key[j]);
    }
    const bool valid = th && (keyv == m);

    const int b = i / KK;
    const float x = (float)(ind % Wd);
    const float y = (float)(ind / Wd);
    const float* rp = regs + (size_t)b * 46 * HW + (size_t)ind;

    const float r0 = fmaxf(rp[0 * HW], 0.0f);
    const float r1 = fmaxf(rp[1 * HW], 0.0f);
    const float r2 = fmaxf(rp[2 * HW], 0.0f);
    const float r3 = fmaxf(rp[3 * HW], 0.0f);
    const float cx = x + rp[4 * HW];
    const float cy = y + rp[5 * HW];
    const float d0 = rp[22 * HW], d1 = rp[23 * HW], d2 = rp[24 * HW];
    float ori[16];
#pragma unroll
    for (int t = 0; t < 16; ++t) ori[t] = rp[(25 + t) * HW];
    const float dep_off = rp[41 * HW];

    const float bx1 = fminf(fmaxf((cx - r0) * 4.0f, 0.0f), 1920.0f);
    const float by1 = fminf(fmaxf((cy - r1) * 4.0f, 0.0f), 1056.0f);
    const float bx2 = fminf(fmaxf((cx + r2) * 4.0f, 0.0f), 1920.0f);
    const float by2 = fminf(fmaxf((cy + r3) * 4.0f, 0.0f), 1056.0f);

    const float dim0 = expf(d0) * DIMM[cls][0];
    const float dim1 = expf(d1) * DIMM[cls][1];
    const float dim2 = expf(d2) * DIMM[cls][2];

    const float sig = 1.0f / (1.0f + expf(-dep_off));
    const float depth = fminf(fmaxf(1.0f / sig - 1.0f, 0.1f), 200.0f);

    const float fu = calib[0], cu = calib[2], fv = calib[5], cv = calib[6];
    const float bxo = calib[3] / -fu;
    const float byo = calib[7] / -fv;
    const float pix = cx * 4.0f, piy = cy * 4.0f;
    const float locx = (pix - cu) * depth / fu + bxo;
    const float locy = (piy - cv) * depth / fv + byo;

    float best = -INFINITY;
    int bidx = 0;
#pragma unroll
    for (int t = 0; t < 4; ++t) {
        const float l0 = ori[2 * t], l1 = ori[2 * t + 1];
        const float mm = fmaxf(l0, l1);
        const float p1 = expf(l1 - mm) / (expf(l0 - mm) + expf(l1 - mm));
        if (p1 > best) { best = p1; bidx = t; }
    }
    const float sel0 = ori[8 + 2 * bidx], sel1 = ori[8 + 2 * bidx + 1];
    float alpha = atanf(sel0 / sel1) + ACENT[bidx];
    const float ray = atanf(locx / depth);
    float roty = alpha + ray;
    if (roty > PI_F) roty -= TWO_PI_F;
    if (roty < -PI_F) roty += TWO_PI_F;
    if (alpha > PI_F) alpha -= TWO_PI_F;
    if (alpha < -PI_F) alpha += TWO_PI_F;

    float* o = out + (size_t)i * 14;
    o[0] = bx1; o[1] = by1; o[2] = bx2; o[3] = by2;
    o[4] = dim0; o[5] = dim1; o[6] = dim2;
    o[7] = depth;
    o[8] = locx; o[9] = locy; o[10] = depth;
    o[11] = roty; o[12] = alpha;
    o[13] = score;
    out[NDET * 14 + i] = valid ? 1.0f : 0.0f;
    out[NDET * 15 + i] = (float)cls;
}

extern "C" void kernel_launch(void* const* d_in, const int* in_sizes, int n_in,
                              void* d_out, int out_size, void* d_ws, size_t ws_size,
                              hipStream_t stream) {
    const float* cls = (const float*)d_in[0];
    const float* regs = (const float*)d_in[1];
    const float* calib = (const float*)d_in[2];
    float* out = (float*)d_out;
    char* ws = (char*)d_ws;

    // ws layout
    int* planeCnt = (int*)ws;                                          // 144*4 = 576 B (pad to 1024)
    unsigned long long* planeList = (unsigned long long*)(ws + 1024);  // 144*6912*8 = 7,962,624 B
    unsigned long long* planeKeys = (unsigned long long*)(ws + 1024 + 7962624);  // 57,600 B
    char* tail = ws + 1024 + 7962624 + 57600;
    float* dScore = (float*)tail;           // 800*4
    int* dInd = (int*)(tail + 3200);        // 800*4
    int* dCls = (int*)(tail + 6400);        // 800*4

    hipMemsetAsync(planeCnt, 0, 1024, stream);
    hipLaunchKernelGGL(nms_compact, dim3(CHUNKS, NPLANE), dim3(256), 0, stream, cls, planeList, planeCnt);
    hipLaunchKernelGGL(plane_topk, dim3(NPLANE), dim3(256), 0, stream, planeList, planeCnt, planeKeys);
    hipLaunchKernelGGL(batch_topk, dim3(NB), dim3(256), 0, stream, planeKeys, dScore, dInd, dCls);
    hipLaunchKernelGGL(finalize_dets, dim3(1), dim3(1024), 0, stream, regs, calib, dScore, dInd, dCls, out);
}

// Round 3
// 317.165 us; speedup vs baseline: 2.5583x; 1.0642x over previous
//
#include <hip/hip_runtime.h>
#include <math.h>

#define Hd 264
#define Wd 480
#define HW (Hd * Wd)
#define NB 16
#define NC 9
#define KK 50
#define NPLANE (NB * NC)
#define NDET (NB * KK)
#define CAP 6912
#define ROWS 8
#define CHUNKS (Hd / ROWS)      // 33
#define STRIPE_CAP 512          // max survivors per 8x480 stripe (<=480 for distinct values)
#define PI_F 3.14159274101257324f
#define TWO_PI_F 6.28318548202514648f

__device__ const float DIMM[9][3] = {
    {3.99331126f, 1.54370861f, 1.64175497f},
    {0.295f, 1.6f, 0.3175f},
    {1.34645161f, 1.55322581f, 0.3883871f},
    {2.503f, 1.72f, 1.077f},
    {9.1775f, 2.95f, 2.3425f},
    {10.3655102f, 3.31632653f, 2.45469388f},
    {6.016911083f, 3.412001685f, 2.2783185f},
    {4.824963f, 2.046904f, 1.78939f},
    {8.8040879f, 2.916193f, 2.07649252f}};

__device__ const float ACENT[4] = {0.0f, 1.57079637050628662f, 3.14159274101257324f, -1.57079637050628662f};

// Kernel 1: NMS over an 8-row stripe of one (b,c) plane; survivors written to a
// private per-(plane,stripe) slab + exact count. No global atomics, nothing to
// pre-zero (count written unconditionally each launch -> graph-replay safe).
// Key = (value_bits << 32) | ~idx  (heat >= 0 so float-bit order == value order;
// ~idx encodes jax.lax.top_k's lower-index-wins tiebreak).
__global__ __launch_bounds__(256) void nms_compact(const float* __restrict__ cls,
                                                   unsigned long long* __restrict__ planeList,
                                                   int* __restrict__ stripeCnt) {
    __shared__ float srows[(ROWS + 4) * Wd];  // 23 KB
    __shared__ float scol[ROWS * Wd];         // 15.4 KB
    __shared__ unsigned long long sbuf[STRIPE_CAP];
    __shared__ int scnt;

    const int plane = blockIdx.y;
    const int chunk = blockIdx.x;
    const int tid = threadIdx.x;
    const float* heat = cls + (size_t)plane * HW;
    const int y0 = chunk * ROWS;

    if (tid == 0) scnt = 0;

    // Stage rows y0-2 .. y0+ROWS+1 (-inf outside) — coalesced.
    for (int j = tid; j < (ROWS + 4) * Wd; j += 256) {
        const int ry = y0 - 2 + j / Wd;
        const int x = j - (j / Wd) * Wd;
        srows[j] = (ry >= 0 && ry < Hd) ? heat[ry * Wd + x] : -INFINITY;
    }
    __syncthreads();

    // Vertical 5-tap max.
    for (int j = tid; j < ROWS * Wd; j += 256) {
        float m = fmaxf(fmaxf(srows[j], srows[j + Wd]), fmaxf(srows[j + 2 * Wd], srows[j + 3 * Wd]));
        scol[j] = fmaxf(m, srows[j + 4 * Wd]);
    }
    __syncthreads();

    // Horizontal 5-tap max + survivor detection.
    for (int j = tid; j < ROWS * Wd; j += 256) {
        const int r = j / Wd;
        const int x = j - r * Wd;
        float hm = scol[j];
        if (x >= 1) hm = fmaxf(hm, scol[j - 1]);
        if (x >= 2) hm = fmaxf(hm, scol[j - 2]);
        if (x <= Wd - 2) hm = fmaxf(hm, scol[j + 1]);
        if (x <= Wd - 3) hm = fmaxf(hm, scol[j + 2]);
        const float v = srows[(r + 2) * Wd + x];
        if (v == hm) {
            const unsigned int idx = (unsigned int)((y0 + r) * Wd + x);
            const unsigned long long key =
                ((unsigned long long)__float_as_uint(v) << 32) | (unsigned long long)(0xFFFFFFFFu - idx);
            const int p = atomicAdd(&scnt, 1);
            if (p < STRIPE_CAP) sbuf[p] = key;
        }
    }
    __syncthreads();
    const int n = min(scnt, STRIPE_CAP);
    const int stripe = plane * CHUNKS + chunk;
    unsigned long long* dst = planeList + (size_t)stripe * STRIPE_CAP;
    for (int j = tid; j < n; j += 256) dst[j] = sbuf[j];
    if (tid == 0) stripeCnt[stripe] = n;
}

// Kernel 2: per-plane exact top-50. Gather the plane's 33 slabs contiguously
// into LDS, then 50 rounds of keyed argmax (remove-by-key, wave-shfl reduce).
__global__ __launch_bounds__(256) void plane_topk(const unsigned long long* __restrict__ planeList,
                                                  const int* __restrict__ stripeCnt,
                                                  unsigned long long* __restrict__ planeKeys) {
    __shared__ unsigned long long cand[CAP];
    __shared__ int soff[CHUNKS + 1];
    __shared__ unsigned long long wmax[4];
    __shared__ unsigned long long sprev;

    const int plane = blockIdx.x;
    const int tid = threadIdx.x;

    if (tid == 0) {
        int acc = 0;
        for (int c = 0; c < CHUNKS; ++c) {
            soff[c] = acc;
            acc += min(stripeCnt[plane * CHUNKS + c], STRIPE_CAP);
        }
        soff[CHUNKS] = acc;
    }
    __syncthreads();

    for (int c = 0; c < CHUNKS; ++c) {
        const int nc = soff[c + 1] - soff[c];
        const unsigned long long* src = planeList + (size_t)(plane * CHUNKS + c) * STRIPE_CAP;
        for (int j = tid; j < nc; j += 256) {
            const int d = soff[c] + j;
            if (d < CAP) cand[d] = src[j];
        }
    }
    __syncthreads();
    const int n = min(soff[CHUNKS], CAP);

    unsigned long long prev = ~0ull;  // > any real key (heat < 2.0)
    for (int it = 0; it < KK; ++it) {
        unsigned long long mk = 0;
        for (int j = tid; j < n; j += 256) {
            unsigned long long k = cand[j];
            if (k == prev) { cand[j] = 0; k = 0; }
            if (k > mk) mk = k;
        }
        for (int s = 32; s > 0; s >>= 1) {
            const unsigned long long o = __shfl_down(mk, s);
            if (o > mk) mk = o;
        }
        if ((tid & 63) == 0) wmax[tid >> 6] = mk;
        __syncthreads();
        if (tid == 0) {
            unsigned long long m = wmax[0];
            if (wmax[1] > m) m = wmax[1];
            if (wmax[2] > m) m = wmax[2];
            if (wmax[3] > m) m = wmax[3];
            planeKeys[plane * KK + it] = m;
            sprev = m;
        }
        __syncthreads();
        prev = sprev;
    }
}

// Kernel 3: per batch — top-50 over 450 (class,rank) candidates; lower
// class-major flat index wins ties (matches top_k on reshaped array).
__global__ __launch_bounds__(256) void batch_topk(const unsigned long long* __restrict__ planeKeys,
                                                  float* __restrict__ dScore, int* __restrict__ dInd,
                                                  int* __restrict__ dCls) {
    __shared__ unsigned long long k2[NC * KK];
    __shared__ unsigned int sidx[NC * KK];
    __shared__ unsigned long long wmax[4];
    __shared__ unsigned long long sprev;

    const int b = blockIdx.x;
    const int tid = threadIdx.x;
    for (int j = tid; j < NC * KK; j += 256) {
        const unsigned long long pk = planeKeys[(b * NC + j / KK) * KK + (j % KK)];
        sidx[j] = 0xFFFFFFFFu - (unsigned int)(pk & 0xFFFFFFFFull);
        k2[j] = (pk & 0xFFFFFFFF00000000ull) | (unsigned long long)(0xFFFFFFFFu - (unsigned int)j);
    }
    __syncthreads();

    unsigned long long prev = ~0ull;
    for (int it = 0; it < KK; ++it) {
        unsigned long long mk = 0;
        for (int j = tid; j < NC * KK; j += 256) {
            unsigned long long k = k2[j];
            if (k == prev) { k2[j] = 0; k = 0; }
            if (k > mk) mk = k;
        }
        for (int s = 32; s > 0; s >>= 1) {
            const unsigned long long o = __shfl_down(mk, s);
            if (o > mk) mk = o;
        }
        if ((tid & 63) == 0) wmax[tid >> 6] = mk;
        __syncthreads();
        if (tid == 0) {
            unsigned long long m = wmax[0];
            if (wmax[1] > m) m = wmax[1];
            if (wmax[2] > m) m = wmax[2];
            if (wmax[3] > m) m = wmax[3];
            const int f = (int)(0xFFFFFFFFu - (unsigned int)(m & 0xFFFFFFFFull));
            dScore[b * KK + it] = __uint_as_float((unsigned int)(m >> 32));
            dInd[b * KK + it] = (int)sidx[f];
            dCls[b * KK + it] = f / KK;
            sprev = m;
        }
        __syncthreads();
        prev = sprev;
    }
}

// Kernel 4: single block — gather regs, batch-global segment-max dedup, per-det math.
__global__ __launch_bounds__(1024) void finalize_dets(const float* __restrict__ regs,
                                                      const float* __restrict__ calib,
                                                      const float* __restrict__ dScore,
                                                      const int* __restrict__ dInd,
                                                      const int* __restrict__ dCls,
                                                      float* __restrict__ out) {
    __shared__ int s_ind[NDET];
    __shared__ float s_key[NDET];

    const int i = threadIdx.x;
    float score = 0.0f, keyv = -INFINITY;
    int ind = 0, cls = 0;
    bool th = false;
    if (i < NDET) {
        score = dScore[i];
        ind = dInd[i];
        cls = dCls[i];
        th = score >= 0.29f;
        keyv = th ? (float)cls * 10000.0f - (float)i : -INFINITY;
        s_ind[i] = ind;
        s_key[i] = keyv;
    }
    __syncthreads();
    if (i >= NDET) return;

    float m = -INFINITY;
    for (int j = 0; j < NDET; ++j) {
        if (s_ind[j] == ind) m = fmaxf(m, s_key[j]);
    }
    const bool valid = th && (keyv == m);

    const int b = i / KK;
    const float x = (float)(ind % Wd);
    const float y = (float)(ind / Wd);
    const float* rp = regs + (size_t)b * 46 * HW + (size_t)ind;

    const float r0 = fmaxf(rp[0 * HW], 0.0f);
    const float r1 = fmaxf(rp[1 * HW], 0.0f);
    const float r2 = fmaxf(rp[2 * HW], 0.0f);
    const float r3 = fmaxf(rp[3 * HW], 0.0f);
    const float cx = x + rp[4 * HW];
    const float cy = y + rp[5 * HW];
    const float d0 = rp[22 * HW], d1 = rp[23 * HW], d2 = rp[24 * HW];
    float ori[16];
#pragma unroll
    for (int t = 0; t < 16; ++t) ori[t] = rp[(25 + t) * HW];
    const float dep_off = rp[41 * HW];

    const float bx1 = fminf(fmaxf((cx - r0) * 4.0f, 0.0f), 1920.0f);
    const float by1 = fminf(fmaxf((cy - r1) * 4.0f, 0.0f), 1056.0f);
    const float bx2 = fminf(fmaxf((cx + r2) * 4.0f, 0.0f), 1920.0f);
    const float by2 = fminf(fmaxf((cy + r3) * 4.0f, 0.0f), 1056.0f);

    const float dim0 = expf(d0) * DIMM[cls][0];
    const float dim1 = expf(d1) * DIMM[cls][1];
    const float dim2 = expf(d2) * DIMM[cls][2];

    const float sig = 1.0f / (1.0f + expf(-dep_off));
    const float depth = fminf(fmaxf(1.0f / sig - 1.0f, 0.1f), 200.0f);

    const float fu = calib[0], cu = calib[2], fv = calib[5], cv = calib[6];
    const float bxo = calib[3] / -fu;
    const float byo = calib[7] / -fv;
    const float pix = cx * 4.0f, piy = cy * 4.0f;
    const float locx = (pix - cu) * depth / fu + bxo;
    const float locy = (piy - cv) * depth / fv + byo;

    float best = -INFINITY;
    int bidx = 0;
#pragma unroll
    for (int t = 0; t < 4; ++t) {
        const float l0 = ori[2 * t], l1 = ori[2 * t + 1];
        const float mm = fmaxf(l0, l1);
        const float p1 = expf(l1 - mm) / (expf(l0 - mm) + expf(l1 - mm));
        if (p1 > best) { best = p1; bidx = t; }
    }
    const float sel0 = ori[8 + 2 * bidx], sel1 = ori[8 + 2 * bidx + 1];
    float alpha = atanf(sel0 / sel1) + ACENT[bidx];
    const float ray = atanf(locx / depth);
    float roty = alpha + ray;
    if (roty > PI_F) roty -= TWO_PI_F;
    if (roty < -PI_F) roty += TWO_PI_F;
    if (alpha > PI_F) alpha -= TWO_PI_F;
    if (alpha < -PI_F) alpha += TWO_PI_F;

    float* o = out + (size_t)i * 14;
    o[0] = bx1; o[1] = by1; o[2] = bx2; o[3] = by2;
    o[4] = dim0; o[5] = dim1; o[6] = dim2;
    o[7] = depth;
    o[8] = locx; o[9] = locy; o[10] = depth;
    o[11] = roty; o[12] = alpha;
    o[13] = score;
    out[NDET * 14 + i] = valid ? 1.0f : 0.0f;
    out[NDET * 15 + i] = (float)cls;
}

extern "C" void kernel_launch(void* const* d_in, const int* in_sizes, int n_in,
                              void* d_out, int out_size, void* d_ws, size_t ws_size,
                              hipStream_t stream) {
    const float* cls = (const float*)d_in[0];
    const float* regs = (const float*)d_in[1];
    const float* calib = (const float*)d_in[2];
    float* out = (float*)d_out;
    char* ws = (char*)d_ws;

    // ws layout (all regions fully rewritten every launch before being read)
    int* stripeCnt = (int*)ws;                                        // 144*33*4 = 19,008 B (pad 32K)
    unsigned long long* planeList = (unsigned long long*)(ws + 32768);  // 144*33*512*8 = 19,464,192 B
    char* tail = ws + 32768 + 19464192;
    unsigned long long* planeKeys = (unsigned long long*)tail;        // 144*50*8 = 57,600 B
    float* dScore = (float*)(tail + 57600);                           // 800*4
    int* dInd = (int*)(tail + 60800);                                 // 800*4
    int* dCls = (int*)(tail + 64000);                                 // 800*4

    hipLaunchKernelGGL(nms_compact, dim3(CHUNKS, NPLANE), dim3(256), 0, stream, cls, planeList, stripeCnt);
    hipLaunchKernelGGL(plane_topk, dim3(NPLANE), dim3(256), 0, stream, planeList, stripeCnt, planeKeys);
    hipLaunchKernelGGL(batch_topk, dim3(NB), dim3(256), 0, stream, planeKeys, dScore, dInd, dCls);
    hipLaunchKernelGGL(finalize_dets, dim3(1), dim3(1024), 0, stream, regs, calib, dScore, dInd, dCls, out);
}

// Round 4
// 277.033 us; speedup vs baseline: 2.9289x; 1.1449x over previous
//
#include <hip/hip_runtime.h>
#include <math.h>

#define Hd 264
#define Wd 480
#define W4 (Wd / 4)
#define HW (Hd * Wd)
#define NB 16
#define NC 9
#define KK 50
#define NPLANE (NB * NC)
#define NDET (NB * KK)
#define CAP 6912
#define ROWS 8
#define CHUNKS (Hd / ROWS)      // 33
#define STRIPE_CAP 512
#define SCAP 1024
#define PI_F 3.14159274101257324f
#define TWO_PI_F 6.28318548202514648f

__device__ const float DIMM[9][3] = {
    {3.99331126f, 1.54370861f, 1.64175497f},
    {0.295f, 1.6f, 0.3175f},
    {1.34645161f, 1.55322581f, 0.3883871f},
    {2.503f, 1.72f, 1.077f},
    {9.1775f, 2.95f, 2.3425f},
    {10.3655102f, 3.31632653f, 2.45469388f},
    {6.016911083f, 3.412001685f, 2.2783185f},
    {4.824963f, 2.046904f, 1.78939f},
    {8.8040879f, 2.916193f, 2.07649252f}};

__device__ const float ACENT[4] = {0.0f, 1.57079637050628662f, 3.14159274101257324f, -1.57079637050628662f};

__device__ __forceinline__ float4 max4(float4 a, float4 b) {
    return make_float4(fmaxf(a.x, b.x), fmaxf(a.y, b.y), fmaxf(a.z, b.z), fmaxf(a.w, b.w));
}

// Kernel 1: 5x5 NMS over an 8-row stripe of one (b,c) plane; survivors to a
// private per-(plane,stripe) slab + exact count (no global atomics, nothing to
// pre-zero). Key = (value_bits << 32) | ~idx — unique per pixel; heat >= 0 so
// float-bit order == value order; ~idx = jax.lax.top_k lower-index-wins tiebreak.
__global__ __launch_bounds__(256) void nms_compact(const float* __restrict__ cls,
                                                   unsigned long long* __restrict__ planeList,
                                                   int* __restrict__ stripeCnt) {
    __shared__ float srows[(ROWS + 4) * Wd];  // 23 KB
    __shared__ float scol[ROWS * Wd];         // 15.4 KB
    __shared__ unsigned long long sbuf[STRIPE_CAP];
    __shared__ int scnt;

    const int plane = blockIdx.y;
    const int chunk = blockIdx.x;
    const int tid = threadIdx.x;
    const float4* heat4 = (const float4*)(cls + (size_t)plane * HW);
    const int y0 = chunk * ROWS;

    if (tid == 0) scnt = 0;

    // Stage rows y0-2 .. y0+ROWS+1 as float4 (-inf outside) — coalesced 16B/lane.
    float4* srows4 = (float4*)srows;
    for (int j = tid; j < (ROWS + 4) * W4; j += 256) {
        const int rr = j / W4;
        const int ry = y0 - 2 + rr;
        const int c4 = j - rr * W4;
        float4 v;
        if (ry >= 0 && ry < Hd) v = heat4[ry * W4 + c4];
        else v = make_float4(-INFINITY, -INFINITY, -INFINITY, -INFINITY);
        srows4[j] = v;
    }
    __syncthreads();

    // Vertical 5-tap max (float4).
    float4* scol4 = (float4*)scol;
    for (int j = tid; j < ROWS * W4; j += 256) {
        float4 m = max4(max4(srows4[j], srows4[j + W4]), max4(srows4[j + 2 * W4], srows4[j + 3 * W4]));
        scol4[j] = max4(m, srows4[j + 4 * W4]);
    }
    __syncthreads();

    // Horizontal 5-tap max + survivor detection (scalar over LDS).
    for (int j = tid; j < ROWS * Wd; j += 256) {
        const int r = j / Wd;
        const int x = j - r * Wd;
        float hm = scol[j];
        if (x >= 1) hm = fmaxf(hm, scol[j - 1]);
        if (x >= 2) hm = fmaxf(hm, scol[j - 2]);
        if (x <= Wd - 2) hm = fmaxf(hm, scol[j + 1]);
        if (x <= Wd - 3) hm = fmaxf(hm, scol[j + 2]);
        const float v = srows[(r + 2) * Wd + x];
        if (v == hm) {
            const unsigned int idx = (unsigned int)((y0 + r) * Wd + x);
            const unsigned long long key =
                ((unsigned long long)__float_as_uint(v) << 32) | (unsigned long long)(0xFFFFFFFFu - idx);
            const int p = atomicAdd(&scnt, 1);
            if (p < STRIPE_CAP) sbuf[p] = key;
        }
    }
    __syncthreads();
    const int n = min(scnt, STRIPE_CAP);
    const int stripe = plane * CHUNKS + chunk;
    unsigned long long* dst = planeList + (size_t)stripe * STRIPE_CAP;
    for (int j = tid; j < n; j += 256) dst[j] = sbuf[j];
    if (tid == 0) stripeCnt[stripe] = n;
}

// Kernel 2: per-plane exact top-50 via radix rank-select.
// Histogram key[63:52] (4096 bins) -> threshold bin b1 (cumulative-from-top >= 50)
// -> compact keys with bin >= b1 (unique u64 keys) -> exact rank = count-greater.
__global__ __launch_bounds__(256) void plane_topk(const unsigned long long* __restrict__ planeList,
                                                  const int* __restrict__ stripeCnt,
                                                  unsigned long long* __restrict__ planeKeys) {
    __shared__ unsigned long long cand[CAP];   // 55.3 KB
    __shared__ int hist[4096];                 // 16 KB
    __shared__ int csum[256];
    __shared__ unsigned long long S[SCAP];     // 8 KB
    __shared__ int soff[CHUNKS + 1];
    __shared__ int s_b1, s_scnt;
    __shared__ unsigned long long wmax[4];
    __shared__ unsigned long long sprev;

    const int plane = blockIdx.x;
    const int tid = threadIdx.x;

    if (tid == 0) {
        int acc = 0;
        for (int c = 0; c < CHUNKS; ++c) {
            soff[c] = acc;
            acc += min(stripeCnt[plane * CHUNKS + c], STRIPE_CAP);
        }
        soff[CHUNKS] = acc;
        s_scnt = 0;
    }
    for (int j = tid; j < 4096; j += 256) hist[j] = 0;
    __syncthreads();

    for (int c = 0; c < CHUNKS; ++c) {
        const int nc = soff[c + 1] - soff[c];
        const unsigned long long* src = planeList + (size_t)(plane * CHUNKS + c) * STRIPE_CAP;
        for (int j = tid; j < nc; j += 256) {
            const int d = soff[c] + j;
            if (d < CAP) cand[d] = src[j];
        }
    }
    __syncthreads();
    const int n = min(soff[CHUNKS], CAP);

    // Histogram on top 12 bits of the key.
    for (int j = tid; j < n; j += 256) atomicAdd(&hist[(unsigned int)(cand[j] >> 52)], 1);
    __syncthreads();
    // Per-thread 16-bin partial sums, then thread-0 walks from the top.
    {
        int s = 0;
#pragma unroll 4
        for (int q = 0; q < 16; ++q) s += hist[tid * 16 + q];
        csum[tid] = s;
    }
    __syncthreads();
    if (tid == 0) {
        int acc = 0, b1 = 0;
        for (int t = 255; t >= 0; --t) {
            if (acc + csum[t] >= KK) {
                for (int b = t * 16 + 15; b >= t * 16; --b) {
                    if (acc + hist[b] >= KK) { b1 = b; break; }
                    acc += hist[b];
                }
                goto done;
            }
            acc += csum[t];
        }
        b1 = 0;  // fewer than KK candidates total
    done:
        s_b1 = b1;
    }
    __syncthreads();
    const int b1 = s_b1;

    // Compact candidates with bin >= b1.
    for (int j = tid; j < n; j += 256) {
        const unsigned long long k = cand[j];
        if ((unsigned int)(k >> 52) >= (unsigned int)b1) {
            const int p = atomicAdd(&s_scnt, 1);
            if (p < SCAP) S[p] = k;
        }
    }
    __syncthreads();
    const int scnt = s_scnt;

    if (scnt <= SCAP) {
        // Exact rank among compacted set (all keys outside S are strictly smaller).
        for (int idx = tid; idx < scnt; idx += 256) {
            const unsigned long long k = S[idx];
            int r = 0;
            for (int j = 0; j < scnt; ++j) r += (S[j] > k) ? 1 : 0;
            if (r < KK) planeKeys[plane * KK + r] = k;
        }
    } else {
        // Fallback (adversarial distribution): 50 rounds of keyed argmax.
        unsigned long long prev = ~0ull;
        for (int it = 0; it < KK; ++it) {
            unsigned long long mk = 0;
            for (int j = tid; j < n; j += 256) {
                unsigned long long k = cand[j];
                if (k == prev) { cand[j] = 0; k = 0; }
                if (k > mk) mk = k;
            }
            for (int s = 32; s > 0; s >>= 1) {
                const unsigned long long o = __shfl_down(mk, s);
                if (o > mk) mk = o;
            }
            if ((tid & 63) == 0) wmax[tid >> 6] = mk;
            __syncthreads();
            if (tid == 0) {
                unsigned long long m = wmax[0];
                if (wmax[1] > m) m = wmax[1];
                if (wmax[2] > m) m = wmax[2];
                if (wmax[3] > m) m = wmax[3];
                planeKeys[plane * KK + it] = m;
                sprev = m;
            }
            __syncthreads();
            prev = sprev;
        }
    }
}

// Kernel 3: per batch — exact top-50 of 450 unique keys by direct ranking.
// Key embeds ~(class-major flat index) -> matches top_k tiebreak on reshaped array.
__global__ __launch_bounds__(256) void batch_topk(const unsigned long long* __restrict__ planeKeys,
                                                  float* __restrict__ dScore, int* __restrict__ dInd,
                                                  int* __restrict__ dCls) {
    __shared__ unsigned long long k2[NC * KK];
    __shared__ unsigned int sidx[NC * KK];

    const int b = blockIdx.x;
    const int tid = threadIdx.x;
    for (int j = tid; j < NC * KK; j += 256) {
        const unsigned long long pk = planeKeys[(b * NC + j / KK) * KK + (j % KK)];
        sidx[j] = 0xFFFFFFFFu - (unsigned int)(pk & 0xFFFFFFFFull);
        k2[j] = (pk & 0xFFFFFFFF00000000ull) | (unsigned long long)(0xFFFFFFFFu - (unsigned int)j);
    }
    __syncthreads();

    for (int idx = tid; idx < NC * KK; idx += 256) {
        const unsigned long long k = k2[idx];
        int r = 0;
        for (int j = 0; j < NC * KK; ++j) r += (k2[j] > k) ? 1 : 0;
        if (r < KK) {
            dScore[b * KK + r] = __uint_as_float((unsigned int)(k >> 32));
            dInd[b * KK + r] = (int)sidx[idx];
            dCls[b * KK + r] = idx / KK;
        }
    }
}

// Kernel 4: single block — gather regs, batch-global segment-max dedup, per-det math.
__global__ __launch_bounds__(1024) void finalize_dets(const float* __restrict__ regs,
                                                      const float* __restrict__ calib,
                                                      const float* __restrict__ dScore,
                                                      const int* __restrict__ dInd,
                                                      const int* __restrict__ dCls,
                                                      float* __restrict__ out) {
    __shared__ int s_ind[NDET];
    __shared__ float s_key[NDET];

    const int i = threadIdx.x;
    float score = 0.0f, keyv = -INFINITY;
    int ind = 0, cls = 0;
    bool th = false;
    if (i < NDET) {
        score = dScore[i];
        ind = dInd[i];
        cls = dCls[i];
        th = score >= 0.29f;
        keyv = th ? (float)cls * 10000.0f - (float)i : -INFINITY;
        s_ind[i] = ind;
        s_key[i] = keyv;
    }
    __syncthreads();
    if (i >= NDET) return;

    float m = -INFINITY;
    for (int j = 0; j < NDET; ++j) {
        if (s_ind[j] == ind) m = fmaxf(m, s_key[j]);
    }
    const bool valid = th && (keyv == m);

    const int b = i / KK;
    const float x = (float)(ind % Wd);
    const float y = (float)(ind / Wd);
    const float* rp = regs + (size_t)b * 46 * HW + (size_t)ind;

    const float r0 = fmaxf(rp[0 * HW], 0.0f);
    const float r1 = fmaxf(rp[1 * HW], 0.0f);
    const float r2 = fmaxf(rp[2 * HW], 0.0f);
    const float r3 = fmaxf(rp[3 * HW], 0.0f);
    const float cx = x + rp[4 * HW];
    const float cy = y + rp[5 * HW];
    const float d0 = rp[22 * HW], d1 = rp[23 * HW], d2 = rp[24 * HW];
    float ori[16];
#pragma unroll
    for (int t = 0; t < 16; ++t) ori[t] = rp[(25 + t) * HW];
    const float dep_off = rp[41 * HW];

    const float bx1 = fminf(fmaxf((cx - r0) * 4.0f, 0.0f), 1920.0f);
    const float by1 = fminf(fmaxf((cy - r1) * 4.0f, 0.0f), 1056.0f);
    const float bx2 = fminf(fmaxf((cx + r2) * 4.0f, 0.0f), 1920.0f);
    const float by2 = fminf(fmaxf((cy + r3) * 4.0f, 0.0f), 1056.0f);

    const float dim0 = expf(d0) * DIMM[cls][0];
    const float dim1 = expf(d1) * DIMM[cls][1];
    const float dim2 = expf(d2) * DIMM[cls][2];

    const float sig = 1.0f / (1.0f + expf(-dep_off));
    const float depth = fminf(fmaxf(1.0f / sig - 1.0f, 0.1f), 200.0f);

    const float fu = calib[0], cu = calib[2], fv = calib[5], cv = calib[6];
    const float bxo = calib[3] / -fu;
    const float byo = calib[7] / -fv;
    const float pix = cx * 4.0f, piy = cy * 4.0f;
    const float locx = (pix - cu) * depth / fu + bxo;
    const float locy = (piy - cv) * depth / fv + byo;

    float best = -INFINITY;
    int bidx = 0;
#pragma unroll
    for (int t = 0; t < 4; ++t) {
        const float l0 = ori[2 * t], l1 = ori[2 * t + 1];
        const float mm = fmaxf(l0, l1);
        const float p1 = expf(l1 - mm) / (expf(l0 - mm) + expf(l1 - mm));
        if (p1 > best) { best = p1; bidx = t; }
    }
    const float sel0 = ori[8 + 2 * bidx], sel1 = ori[8 + 2 * bidx + 1];
    float alpha = atanf(sel0 / sel1) + ACENT[bidx];
    const float ray = atanf(locx / depth);
    float roty = alpha + ray;
    if (roty > PI_F) roty -= TWO_PI_F;
    if (roty < -PI_F) roty += TWO_PI_F;
    if (alpha > PI_F) alpha -= TWO_PI_F;
    if (alpha < -PI_F) alpha += TWO_PI_F;

    float* o = out + (size_t)i * 14;
    o[0] = bx1; o[1] = by1; o[2] = bx2; o[3] = by2;
    o[4] = dim0; o[5] = dim1; o[6] = dim2;
    o[7] = depth;
    o[8] = locx; o[9] = locy; o[10] = depth;
    o[11] = roty; o[12] = alpha;
    o[13] = score;
    out[NDET * 14 + i] = valid ? 1.0f : 0.0f;
    out[NDET * 15 + i] = (float)cls;
}

extern "C" void kernel_launch(void* const* d_in, const int* in_sizes, int n_in,
                              void* d_out, int out_size, void* d_ws, size_t ws_size,
                              hipStream_t stream) {
    const float* cls = (const float*)d_in[0];
    const float* regs = (const float*)d_in[1];
    const float* calib = (const float*)d_in[2];
    float* out = (float*)d_out;
    char* ws = (char*)d_ws;

    // ws layout (all regions fully rewritten every launch before being read)
    int* stripeCnt = (int*)ws;                                          // 144*33*4 B
    unsigned long long* planeList = (unsigned long long*)(ws + 32768);  // 144*33*512*8 B
    char* tail = ws + 32768 + 19464192;
    unsigned long long* planeKeys = (unsigned long long*)tail;          // 144*50*8 B
    float* dScore = (float*)(tail + 57600);
    int* dInd = (int*)(tail + 60800);
    int* dCls = (int*)(tail + 64000);

    hipLaunchKernelGGL(nms_compact, dim3(CHUNKS, NPLANE), dim3(256), 0, stream, cls, planeList, stripeCnt);
    hipLaunchKernelGGL(plane_topk, dim3(NPLANE), dim3(256), 0, stream, planeList, stripeCnt, planeKeys);
    hipLaunchKernelGGL(batch_topk, dim3(NB), dim3(256), 0, stream, planeKeys, dScore, dInd, dCls);
    hipLaunchKernelGGL(finalize_dets, dim3(1), dim3(1024), 0, stream, regs, calib, dScore, dInd, dCls, out);
}

// Round 5
// 125.665 us; speedup vs baseline: 6.4568x; 2.2045x over previous
//
#include <hip/hip_runtime.h>
#include <math.h>

#define Hd 264
#define Wd 480
#define W4 (Wd / 4)
#define HW (Hd * Wd)
#define NB 16
#define NC 9
#define KK 50
#define NPLANE (NB * NC)
#define NDET (NB * KK)
#define CAP 6912
#define ROWS 8
#define CHUNKS (Hd / ROWS)      // 33
#define STRIPE_CAP 512
#define SCAP 1024
#define PI_F 3.14159274101257324f
#define TWO_PI_F 6.28318548202514648f

__device__ const float DIMM[9][3] = {
    {3.99331126f, 1.54370861f, 1.64175497f},
    {0.295f, 1.6f, 0.3175f},
    {1.34645161f, 1.55322581f, 0.3883871f},
    {2.503f, 1.72f, 1.077f},
    {9.1775f, 2.95f, 2.3425f},
    {10.3655102f, 3.31632653f, 2.45469388f},
    {6.016911083f, 3.412001685f, 2.2783185f},
    {4.824963f, 2.046904f, 1.78939f},
    {8.8040879f, 2.916193f, 2.07649252f}};

__device__ const float ACENT[4] = {0.0f, 1.57079637050628662f, 3.14159274101257324f, -1.57079637050628662f};

__device__ __forceinline__ float4 max4(float4 a, float4 b) {
    return make_float4(fmaxf(a.x, b.x), fmaxf(a.y, b.y), fmaxf(a.z, b.z), fmaxf(a.w, b.w));
}

// Kernel 1: 5x5 NMS over an 8-row stripe of one (b,c) plane; survivors to a
// private per-(plane,stripe) slab + exact count. Key = (value_bits<<32) | ~idx
// (heat >= 0 so float-bit order == value order; ~idx = lower-index-wins tiebreak).
__global__ __launch_bounds__(256) void nms_compact(const float* __restrict__ cls,
                                                   unsigned long long* __restrict__ planeList,
                                                   int* __restrict__ stripeCnt) {
    __shared__ float srows[(ROWS + 4) * Wd];
    __shared__ float scol[ROWS * Wd];
    __shared__ unsigned long long sbuf[STRIPE_CAP];
    __shared__ int scnt;

    const int plane = blockIdx.y;
    const int chunk = blockIdx.x;
    const int tid = threadIdx.x;
    const float4* heat4 = (const float4*)(cls + (size_t)plane * HW);
    const int y0 = chunk * ROWS;

    if (tid == 0) scnt = 0;

    float4* srows4 = (float4*)srows;
    for (int j = tid; j < (ROWS + 4) * W4; j += 256) {
        const int rr = j / W4;
        const int ry = y0 - 2 + rr;
        const int c4 = j - rr * W4;
        float4 v;
        if (ry >= 0 && ry < Hd) v = heat4[ry * W4 + c4];
        else v = make_float4(-INFINITY, -INFINITY, -INFINITY, -INFINITY);
        srows4[j] = v;
    }
    __syncthreads();

    float4* scol4 = (float4*)scol;
    for (int j = tid; j < ROWS * W4; j += 256) {
        float4 m = max4(max4(srows4[j], srows4[j + W4]), max4(srows4[j + 2 * W4], srows4[j + 3 * W4]));
        scol4[j] = max4(m, srows4[j + 4 * W4]);
    }
    __syncthreads();

    for (int j = tid; j < ROWS * Wd; j += 256) {
        const int r = j / Wd;
        const int x = j - r * Wd;
        float hm = scol[j];
        if (x >= 1) hm = fmaxf(hm, scol[j - 1]);
        if (x >= 2) hm = fmaxf(hm, scol[j - 2]);
        if (x <= Wd - 2) hm = fmaxf(hm, scol[j + 1]);
        if (x <= Wd - 3) hm = fmaxf(hm, scol[j + 2]);
        const float v = srows[(r + 2) * Wd + x];
        if (v == hm) {
            const unsigned int idx = (unsigned int)((y0 + r) * Wd + x);
            const unsigned long long key =
                ((unsigned long long)__float_as_uint(v) << 32) | (unsigned long long)(0xFFFFFFFFu - idx);
            const int p = atomicAdd(&scnt, 1);
            if (p < STRIPE_CAP) sbuf[p] = key;
        }
    }
    __syncthreads();
    const int n = min(scnt, STRIPE_CAP);
    const int stripe = plane * CHUNKS + chunk;
    unsigned long long* dst = planeList + (size_t)stripe * STRIPE_CAP;
    for (int j = tid; j < n; j += 256) dst[j] = sbuf[j];
    if (tid == 0) stripeCnt[stripe] = n;
}

// Kernel 2: per-plane exact top-50 via TWO-LEVEL radix rank-select.
// Level 1: 4096 bins on key[63:52]. If the selected prefix-set is too big
// (survivor values cluster near 1.0 -> one bin holds ~80%), refine the
// threshold bin on key[51:40]. Compacted set is prefix-closed, so rank =
// count-greater within the set == global rank. Bit-exact selection.
__global__ __launch_bounds__(256) void plane_topk(const unsigned long long* __restrict__ planeList,
                                                  const int* __restrict__ stripeCnt,
                                                  unsigned long long* __restrict__ planeKeys) {
    __shared__ unsigned long long cand[CAP];   // 55.3 KB
    __shared__ int hist[4096];                 // 16 KB
    __shared__ int csum[256];
    __shared__ unsigned long long S[SCAP];     // 8 KB
    __shared__ int soff[CHUNKS + 1];
    __shared__ int s_b1, s_acc, s_b2, s_scnt, s_need2;
    __shared__ unsigned long long wmax[4];
    __shared__ unsigned long long sprev;

    const int plane = blockIdx.x;
    const int tid = threadIdx.x;

    // Parallel stripe-count load + serial 33-add prefix (trivial).
    if (tid < CHUNKS) soff[tid + 1] = min(stripeCnt[plane * CHUNKS + tid], STRIPE_CAP);
    if (tid == 0) { soff[0] = 0; s_scnt = 0; }
    for (int j = tid; j < 4096; j += 256) hist[j] = 0;
    __syncthreads();
    if (tid == 0) {
        for (int c = 1; c <= CHUNKS; ++c) soff[c] += soff[c - 1];
    }
    __syncthreads();
    const int n = min(soff[CHUNKS], CAP);

    // Gather all stripes via per-element binary search (fully parallel).
    for (int j = tid; j < n; j += 256) {
        int lo = 0, hi = CHUNKS;
        while (hi - lo > 1) { const int mid = (lo + hi) >> 1; if (soff[mid] <= j) lo = mid; else hi = mid; }
        cand[j] = planeList[(size_t)(plane * CHUNKS + lo) * STRIPE_CAP + (j - soff[lo])];
    }
    __syncthreads();

    // Level-1 histogram on key[63:52].
    for (int j = tid; j < n; j += 256) atomicAdd(&hist[(unsigned int)(cand[j] >> 52)], 1);
    __syncthreads();
    {
        int s = 0;
#pragma unroll 4
        for (int q = 0; q < 16; ++q) s += hist[tid * 16 + q];
        csum[tid] = s;
    }
    __syncthreads();
    if (tid == 0) {
        int acc = 0, b1 = 0;
        int t = 255;
        for (; t >= 0; --t) { if (acc + csum[t] >= KK) break; acc += csum[t]; }
        if (t < 0) { b1 = 0; } else {
            int b = t * 16 + 15;
            for (; b > t * 16; --b) { if (acc + hist[b] >= KK) break; acc += hist[b]; }
            b1 = b;
        }
        s_b1 = b1;
        s_acc = acc;                             // count of keys with prefix > b1
        s_need2 = (acc + hist[b1] > SCAP) ? 1 : 0;
    }
    __syncthreads();
    const int b1 = s_b1;
    const int need2 = s_need2;
    int b2 = 0;

    if (need2) {
        // Level-2 histogram on key[51:40], restricted to prefix == b1.
        for (int j = tid; j < 4096; j += 256) hist[j] = 0;
        __syncthreads();
        for (int j = tid; j < n; j += 256) {
            const unsigned long long k = cand[j];
            if ((unsigned int)(k >> 52) == (unsigned int)b1)
                atomicAdd(&hist[(unsigned int)(k >> 40) & 0xFFFu], 1);
        }
        __syncthreads();
        {
            int s = 0;
#pragma unroll 4
            for (int q = 0; q < 16; ++q) s += hist[tid * 16 + q];
            csum[tid] = s;
        }
        __syncthreads();
        if (tid == 0) {
            const int target = KK - s_acc;       // >= 1
            int acc2 = 0, bb = 0;
            int t = 255;
            for (; t >= 0; --t) { if (acc2 + csum[t] >= target) break; acc2 += csum[t]; }
            if (t < 0) { bb = 0; } else {
                int b = t * 16 + 15;
                for (; b > t * 16; --b) { if (acc2 + hist[b] >= target) break; acc2 += hist[b]; }
                bb = b;
            }
            s_b2 = bb;
        }
        __syncthreads();
        b2 = s_b2;
    }

    // Compact the prefix-closed selected set.
    for (int j = tid; j < n; j += 256) {
        const unsigned long long k = cand[j];
        const unsigned int p1 = (unsigned int)(k >> 52);
        bool sel;
        if (!need2) sel = (p1 >= (unsigned int)b1);
        else sel = (p1 > (unsigned int)b1) ||
                   (p1 == (unsigned int)b1 && ((unsigned int)(k >> 40) & 0xFFFu) >= (unsigned int)b2);
        if (sel) {
            const int p = atomicAdd(&s_scnt, 1);
            if (p < SCAP) S[p] = k;
        }
    }
    // Zero-pad output slots (overwritten below when enough candidates; safety).
    for (int j = tid; j < KK; j += 256) planeKeys[plane * KK + j] = 0;
    __syncthreads();
    const int scnt = s_scnt;

    if (scnt <= SCAP) {
        // Exact rank = count-greater within compacted set (keys unique).
        for (int idx = tid; idx < scnt; idx += 256) {
            const unsigned long long k = S[idx];
            int r = 0;
            for (int j = 0; j < scnt; ++j) r += (S[j] > k) ? 1 : 0;
            if (r < KK) planeKeys[plane * KK + r] = k;
        }
    } else {
        // Adversarial fallback: 50 rounds of keyed argmax.
        unsigned long long prev = ~0ull;
        for (int it = 0; it < KK; ++it) {
            unsigned long long mk = 0;
            for (int j = tid; j < n; j += 256) {
                unsigned long long k = cand[j];
                if (k == prev) { cand[j] = 0; k = 0; }
                if (k > mk) mk = k;
            }
            for (int s = 32; s > 0; s >>= 1) {
                const unsigned long long o = __shfl_down(mk, s);
                if (o > mk) mk = o;
            }
            if ((tid & 63) == 0) wmax[tid >> 6] = mk;
            __syncthreads();
            if (tid == 0) {
                unsigned long long m = wmax[0];
                if (wmax[1] > m) m = wmax[1];
                if (wmax[2] > m) m = wmax[2];
                if (wmax[3] > m) m = wmax[3];
                planeKeys[plane * KK + it] = m;
                sprev = m;
            }
            __syncthreads();
            prev = sprev;
        }
    }
}

// Kernel 3: per batch — exact top-50 of 450 unique keys by direct ranking.
__global__ __launch_bounds__(256) void batch_topk(const unsigned long long* __restrict__ planeKeys,
                                                  float* __restrict__ dScore, int* __restrict__ dInd,
                                                  int* __restrict__ dCls) {
    __shared__ unsigned long long k2[NC * KK];
    __shared__ unsigned int sidx[NC * KK];

    const int b = blockIdx.x;
    const int tid = threadIdx.x;
    for (int j = tid; j < NC * KK; j += 256) {
        const unsigned long long pk = planeKeys[(b * NC + j / KK) * KK + (j % KK)];
        sidx[j] = 0xFFFFFFFFu - (unsigned int)(pk & 0xFFFFFFFFull);
        k2[j] = (pk & 0xFFFFFFFF00000000ull) | (unsigned long long)(0xFFFFFFFFu - (unsigned int)j);
    }
    __syncthreads();

    for (int idx = tid; idx < NC * KK; idx += 256) {
        const unsigned long long k = k2[idx];
        int r = 0;
        for (int j = 0; j < NC * KK; ++j) r += (k2[j] > k) ? 1 : 0;
        if (r < KK) {
            dScore[b * KK + r] = __uint_as_float((unsigned int)(k >> 32));
            dInd[b * KK + r] = (int)sidx[idx];
            dCls[b * KK + r] = idx / KK;
        }
    }
}

// Kernel 4: one block per detection; lane = channel (26 parallel scattered loads),
// lane 0 does the per-det math. Writes out rows 0..13 and the cls row.
__global__ __launch_bounds__(64) void det_math(const float* __restrict__ regs,
                                               const float* __restrict__ calib,
                                               const float* __restrict__ dScore,
                                               const int* __restrict__ dInd,
                                               const int* __restrict__ dCls,
                                               float* __restrict__ out) {
    __shared__ float s[26];
    const int i = blockIdx.x;
    const int lane = threadIdx.x;
    const int ind = dInd[i];
    const int b = i / KK;
    if (lane < 26) {
        const int ch = (lane < 6) ? lane : lane + 16;  // 0-5, 22-24, 25-40, 41
        s[lane] = regs[(size_t)b * 46 * HW + (size_t)ch * HW + (size_t)ind];
    }
    __syncthreads();
    if (lane != 0) return;

    const int cls = dCls[i];
    const float score = dScore[i];
    const float x = (float)(ind % Wd);
    const float y = (float)(ind / Wd);

    const float r0 = fmaxf(s[0], 0.0f), r1 = fmaxf(s[1], 0.0f);
    const float r2 = fmaxf(s[2], 0.0f), r3 = fmaxf(s[3], 0.0f);
    const float cx = x + s[4];
    const float cy = y + s[5];

    const float bx1 = fminf(fmaxf((cx - r0) * 4.0f, 0.0f), 1920.0f);
    const float by1 = fminf(fmaxf((cy - r1) * 4.0f, 0.0f), 1056.0f);
    const float bx2 = fminf(fmaxf((cx + r2) * 4.0f, 0.0f), 1920.0f);
    const float by2 = fminf(fmaxf((cy + r3) * 4.0f, 0.0f), 1056.0f);

    const float dim0 = expf(s[6]) * DIMM[cls][0];
    const float dim1 = expf(s[7]) * DIMM[cls][1];
    const float dim2 = expf(s[8]) * DIMM[cls][2];

    const float sig = 1.0f / (1.0f + expf(-s[25]));
    const float depth = fminf(fmaxf(1.0f / sig - 1.0f, 0.1f), 200.0f);

    const float fu = calib[0], cu = calib[2], fv = calib[5], cv = calib[6];
    const float bxo = calib[3] / -fu;
    const float byo = calib[7] / -fv;
    const float locx = (cx * 4.0f - cu) * depth / fu + bxo;
    const float locy = (cy * 4.0f - cv) * depth / fv + byo;

    float best = -INFINITY;
    int bidx = 0;
#pragma unroll
    for (int t = 0; t < 4; ++t) {
        const float l0 = s[9 + 2 * t], l1 = s[9 + 2 * t + 1];
        const float mm = fmaxf(l0, l1);
        const float p1 = expf(l1 - mm) / (expf(l0 - mm) + expf(l1 - mm));
        if (p1 > best) { best = p1; bidx = t; }
    }
    const float sel0 = s[9 + 8 + 2 * bidx], sel1 = s[9 + 8 + 2 * bidx + 1];
    float alpha = atanf(sel0 / sel1) + ACENT[bidx];
    const float ray = atanf(locx / depth);
    float roty = alpha + ray;
    if (roty > PI_F) roty -= TWO_PI_F;
    if (roty < -PI_F) roty += TWO_PI_F;
    if (alpha > PI_F) alpha -= TWO_PI_F;
    if (alpha < -PI_F) alpha += TWO_PI_F;

    float* o = out + (size_t)i * 14;
    o[0] = bx1; o[1] = by1; o[2] = bx2; o[3] = by2;
    o[4] = dim0; o[5] = dim1; o[6] = dim2;
    o[7] = depth;
    o[8] = locx; o[9] = locy; o[10] = depth;
    o[11] = roty; o[12] = alpha;
    o[13] = score;
    out[NDET * 15 + i] = (float)cls;
}

// Kernel 5: one block per detection — batch-global segment-max dedup (valid flag).
__global__ __launch_bounds__(64) void valid_seg(const float* __restrict__ dScore,
                                                const int* __restrict__ dInd,
                                                const int* __restrict__ dCls,
                                                float* __restrict__ out) {
    const int i = blockIdx.x;
    const int lane = threadIdx.x;
    const int ind = dInd[i];
    const float score = dScore[i];
    const bool th = score >= 0.29f;
    const float key_i = th ? (float)dCls[i] * 10000.0f - (float)i : -INFINITY;

    float m = -INFINITY;
    for (int j = lane; j < NDET; j += 64) {
        if (dInd[j] == ind && dScore[j] >= 0.29f) {
            const float kj = (float)dCls[j] * 10000.0f - (float)j;
            m = fmaxf(m, kj);
        }
    }
#pragma unroll
    for (int s = 32; s > 0; s >>= 1) m = fmaxf(m, __shfl_down(m, s));
    if (lane == 0) out[NDET * 14 + i] = (th && key_i == m) ? 1.0f : 0.0f;
}

extern "C" void kernel_launch(void* const* d_in, const int* in_sizes, int n_in,
                              void* d_out, int out_size, void* d_ws, size_t ws_size,
                              hipStream_t stream) {
    const float* cls = (const float*)d_in[0];
    const float* regs = (const float*)d_in[1];
    const float* calib = (const float*)d_in[2];
    float* out = (float*)d_out;
    char* ws = (char*)d_ws;

    int* stripeCnt = (int*)ws;                                          // 144*33*4 B
    unsigned long long* planeList = (unsigned long long*)(ws + 32768);  // 144*33*512*8 B
    char* tail = ws + 32768 + 19464192;
    unsigned long long* planeKeys = (unsigned long long*)tail;          // 144*50*8 B
    float* dScore = (float*)(tail + 57600);
    int* dInd = (int*)(tail + 60800);
    int* dCls = (int*)(tail + 64000);

    hipLaunchKernelGGL(nms_compact, dim3(CHUNKS, NPLANE), dim3(256), 0, stream, cls, planeList, stripeCnt);
    hipLaunchKernelGGL(plane_topk, dim3(NPLANE), dim3(256), 0, stream, planeList, stripeCnt, planeKeys);
    hipLaunchKernelGGL(batch_topk, dim3(NB), dim3(256), 0, stream, planeKeys, dScore, dInd, dCls);
    hipLaunchKernelGGL(det_math, dim3(NDET), dim3(64), 0, stream, regs, calib, dScore, dInd, dCls, out);
    hipLaunchKernelGGL(valid_seg, dim3(NDET), dim3(64), 0, stream, dScore, dInd, dCls, out);
}

// Round 6
// 95.414 us; speedup vs baseline: 8.5040x; 1.3171x over previous
//
#include <hip/hip_runtime.h>
#include <math.h>

#define Hd 264
#define Wd 480
#define W4 (Wd / 4)            // 120
#define HW (Hd * Wd)
#define NB 16
#define NC 9
#define KK 50
#define NPLANE (NB * NC)
#define NDET (NB * KK)
#define CAP 6912
#define STRIP 33
#define NCHUNK (Hd / STRIP)    // 8
#define SLAB_CAP 2048          // >= 11*160 distinct-value bound per 33-row stripe
#define SCAP 1024
#define PI_F 3.14159274101257324f
#define TWO_PI_F 6.28318548202514648f

__device__ const float DIMM[9][3] = {
    {3.99331126f, 1.54370861f, 1.64175497f},
    {0.295f, 1.6f, 0.3175f},
    {1.34645161f, 1.55322581f, 0.3883871f},
    {2.503f, 1.72f, 1.077f},
    {9.1775f, 2.95f, 2.3425f},
    {10.3655102f, 3.31632653f, 2.45469388f},
    {6.016911083f, 3.412001685f, 2.2783185f},
    {4.824963f, 2.046904f, 1.78939f},
    {8.8040879f, 2.916193f, 2.07649252f}};

__device__ const float ACENT[4] = {0.0f, 1.57079637050628662f, 3.14159274101257324f, -1.57079637050628662f};

__device__ __forceinline__ float4 max4(float4 a, float4 b) {
    return make_float4(fmaxf(a.x, b.x), fmaxf(a.y, b.y), fmaxf(a.z, b.z), fmaxf(a.w, b.w));
}

// Kernel 1: streaming 5x5 NMS. Block = 128 lanes (lane = float4 column group),
// streams a 33-row stripe + 4 halo rows. Vertical 5-tap max in a register ring;
// horizontal 5-tap via a tiny double-buffered LDS row (1 barrier/row). Survivors
// appended to a per-(plane,chunk) slab + exact count (graph-replay safe).
// Key = (value_bits<<32) | ~idx (heat>=0 -> bit order == value order; ~idx =
// jax.lax.top_k lower-index-wins tiebreak).
__global__ __launch_bounds__(128) void nms_stream(const float* __restrict__ cls,
                                                  unsigned long long* __restrict__ slabs,
                                                  int* __restrict__ slabCnt) {
    __shared__ float rowbuf[2][488];   // [2..481] = vmax cols 0..479; pads -inf
    __shared__ unsigned long long sbuf[SLAB_CAP];
    __shared__ int scnt;

    const int plane = blockIdx.y;
    const int chunk = blockIdx.x;
    const int lane = threadIdx.x;          // 0..127, active: <120
    const bool act = lane < W4;
    const float4* heat4 = (const float4*)(cls + (size_t)plane * HW);
    const int gy0 = chunk * STRIP;

    if (lane < 2) { rowbuf[0][lane] = -INFINITY; rowbuf[1][lane] = -INFINITY; }
    if (lane < 6) { rowbuf[0][482 + lane] = -INFINITY; rowbuf[1][482 + lane] = -INFINITY; }
    if (lane == 0) scnt = 0;

    const float4 NEG = make_float4(-INFINITY, -INFINITY, -INFINITY, -INFINITY);
    float4 r0 = NEG, r1 = NEG, r2 = NEG, r3 = NEG, r4 = NEG;

    // 1-row software prefetch.
    float4 nxt;
    {
        const int ry = gy0 - 2;
        nxt = (act && ry >= 0) ? heat4[ry * W4 + lane] : NEG;
    }

    for (int t = 0; t < STRIP + 4; ++t) {
        const float4 cur = nxt;
        if (t < STRIP + 3) {
            const int ry = gy0 - 1 + t;
            nxt = (act && ry >= 0 && ry < Hd) ? heat4[ry * W4 + lane] : NEG;
        }
        r0 = r1; r1 = r2; r2 = r3; r3 = r4; r4 = cur;
        if (t < 4) continue;

        const int buf = t & 1;
        if (act) {
            const float4 vm = max4(max4(r0, r1), max4(max4(r2, r3), r4));
            *(float2*)&rowbuf[buf][2 + 4 * lane] = make_float2(vm.x, vm.y);
            *(float2*)&rowbuf[buf][4 + 4 * lane] = make_float2(vm.z, vm.w);
        }
        __syncthreads();
        if (act) {
            const float4 a = *(const float4*)&rowbuf[buf][4 * lane];       // cols 4x-2..4x+1
            const float4 b = *(const float4*)&rowbuf[buf][4 * lane + 4];   // cols 4x+2..4x+5
            const float c = fmaxf(fmaxf(a.z, a.w), b.x);
            const float h0 = fmaxf(fmaxf(a.x, a.y), c);
            const float h1 = fmaxf(fmaxf(a.y, b.y), c);
            const float h2 = fmaxf(fmaxf(b.y, b.z), c);
            const float h3 = fmaxf(fmaxf(fmaxf(a.w, b.x), fmaxf(b.y, b.z)), b.w);
            const int gy = gy0 + t - 4;
            const unsigned int base = (unsigned int)(gy * Wd + 4 * lane);
            if (r2.x == h0) {
                const int p = atomicAdd(&scnt, 1);
                if (p < SLAB_CAP) sbuf[p] = ((unsigned long long)__float_as_uint(r2.x) << 32) |
                                            (unsigned long long)(0xFFFFFFFFu - base);
            }
            if (r2.y == h1) {
                const int p = atomicAdd(&scnt, 1);
                if (p < SLAB_CAP) sbuf[p] = ((unsigned long long)__float_as_uint(r2.y) << 32) |
                                            (unsigned long long)(0xFFFFFFFFu - (base + 1));
            }
            if (r2.z == h2) {
                const int p = atomicAdd(&scnt, 1);
                if (p < SLAB_CAP) sbuf[p] = ((unsigned long long)__float_as_uint(r2.z) << 32) |
                                            (unsigned long long)(0xFFFFFFFFu - (base + 2));
            }
            if (r2.w == h3) {
                const int p = atomicAdd(&scnt, 1);
                if (p < SLAB_CAP) sbuf[p] = ((unsigned long long)__float_as_uint(r2.w) << 32) |
                                            (unsigned long long)(0xFFFFFFFFu - (base + 3));
            }
        }
    }
    __syncthreads();
    const int n = min(scnt, SLAB_CAP);
    const int slab = plane * NCHUNK + chunk;
    unsigned long long* dst = slabs + (size_t)slab * SLAB_CAP;
    for (int j = lane; j < n; j += 128) dst[j] = sbuf[j];
    if (lane == 0) slabCnt[slab] = n;
}

// Kernel 2: per-plane exact top-50 via two-level radix rank-select (bit-exact).
__global__ __launch_bounds__(256) void plane_topk(const unsigned long long* __restrict__ slabs,
                                                  const int* __restrict__ slabCnt,
                                                  unsigned long long* __restrict__ planeKeys) {
    __shared__ unsigned long long cand[CAP];   // 55.3 KB
    __shared__ int hist[4096];                 // 16 KB
    __shared__ int csum[256];
    __shared__ unsigned long long S[SCAP];     // 8 KB
    __shared__ int soff[NCHUNK + 1];
    __shared__ int s_b1, s_acc, s_b2, s_scnt, s_need2;
    __shared__ unsigned long long wmax[4];
    __shared__ unsigned long long sprev;

    const int plane = blockIdx.x;
    const int tid = threadIdx.x;

    if (tid < NCHUNK) soff[tid + 1] = min(slabCnt[plane * NCHUNK + tid], SLAB_CAP);
    if (tid == 0) { soff[0] = 0; s_scnt = 0; }
    for (int j = tid; j < 4096; j += 256) hist[j] = 0;
    __syncthreads();
    if (tid == 0) {
        for (int c = 1; c <= NCHUNK; ++c) soff[c] += soff[c - 1];
    }
    __syncthreads();
    const int n = min(soff[NCHUNK], CAP);

    // Gather the 8 slabs via per-element binary search.
    for (int j = tid; j < n; j += 256) {
        int lo = 0, hi = NCHUNK;
        while (hi - lo > 1) { const int mid = (lo + hi) >> 1; if (soff[mid] <= j) lo = mid; else hi = mid; }
        cand[j] = slabs[(size_t)(plane * NCHUNK + lo) * SLAB_CAP + (j - soff[lo])];
    }
    __syncthreads();

    // Level-1 histogram on key[63:52].
    for (int j = tid; j < n; j += 256) atomicAdd(&hist[(unsigned int)(cand[j] >> 52)], 1);
    __syncthreads();
    {
        int s = 0;
#pragma unroll 4
        for (int q = 0; q < 16; ++q) s += hist[tid * 16 + q];
        csum[tid] = s;
    }
    __syncthreads();
    if (tid == 0) {
        int acc = 0, b1 = 0;
        int t = 255;
        for (; t >= 0; --t) { if (acc + csum[t] >= KK) break; acc += csum[t]; }
        if (t < 0) { b1 = 0; } else {
            int b = t * 16 + 15;
            for (; b > t * 16; --b) { if (acc + hist[b] >= KK) break; acc += hist[b]; }
            b1 = b;
        }
        s_b1 = b1;
        s_acc = acc;
        s_need2 = (acc + hist[b1] > SCAP) ? 1 : 0;
    }
    __syncthreads();
    const int b1 = s_b1;
    const int need2 = s_need2;
    int b2 = 0;

    if (need2) {
        for (int j = tid; j < 4096; j += 256) hist[j] = 0;
        __syncthreads();
        for (int j = tid; j < n; j += 256) {
            const unsigned long long k = cand[j];
            if ((unsigned int)(k >> 52) == (unsigned int)b1)
                atomicAdd(&hist[(unsigned int)(k >> 40) & 0xFFFu], 1);
        }
        __syncthreads();
        {
            int s = 0;
#pragma unroll 4
            for (int q = 0; q < 16; ++q) s += hist[tid * 16 + q];
            csum[tid] = s;
        }
        __syncthreads();
        if (tid == 0) {
            const int target = KK - s_acc;
            int acc2 = 0, bb = 0;
            int t = 255;
            for (; t >= 0; --t) { if (acc2 + csum[t] >= target) break; acc2 += csum[t]; }
            if (t < 0) { bb = 0; } else {
                int b = t * 16 + 15;
                for (; b > t * 16; --b) { if (acc2 + hist[b] >= target) break; acc2 += hist[b]; }
                bb = b;
            }
            s_b2 = bb;
        }
        __syncthreads();
        b2 = s_b2;
    }

    for (int j = tid; j < n; j += 256) {
        const unsigned long long k = cand[j];
        const unsigned int p1 = (unsigned int)(k >> 52);
        bool sel;
        if (!need2) sel = (p1 >= (unsigned int)b1);
        else sel = (p1 > (unsigned int)b1) ||
                   (p1 == (unsigned int)b1 && ((unsigned int)(k >> 40) & 0xFFFu) >= (unsigned int)b2);
        if (sel) {
            const int p = atomicAdd(&s_scnt, 1);
            if (p < SCAP) S[p] = k;
        }
    }
    for (int j = tid; j < KK; j += 256) planeKeys[plane * KK + j] = 0;
    __syncthreads();
    const int scnt = s_scnt;

    if (scnt <= SCAP) {
        for (int idx = tid; idx < scnt; idx += 256) {
            const unsigned long long k = S[idx];
            int r = 0;
            for (int j = 0; j < scnt; ++j) r += (S[j] > k) ? 1 : 0;
            if (r < KK) planeKeys[plane * KK + r] = k;
        }
    } else {
        unsigned long long prev = ~0ull;
        for (int it = 0; it < KK; ++it) {
            unsigned long long mk = 0;
            for (int j = tid; j < n; j += 256) {
                unsigned long long k = cand[j];
                if (k == prev) { cand[j] = 0; k = 0; }
                if (k > mk) mk = k;
            }
            for (int s = 32; s > 0; s >>= 1) {
                const unsigned long long o = __shfl_down(mk, s);
                if (o > mk) mk = o;
            }
            if ((tid & 63) == 0) wmax[tid >> 6] = mk;
            __syncthreads();
            if (tid == 0) {
                unsigned long long m = wmax[0];
                if (wmax[1] > m) m = wmax[1];
                if (wmax[2] > m) m = wmax[2];
                if (wmax[3] > m) m = wmax[3];
                planeKeys[plane * KK + it] = m;
                sprev = m;
            }
            __syncthreads();
            prev = sprev;
        }
    }
}

// Kernel 3: per batch — exact top-50 of 450 unique keys by direct ranking.
__global__ __launch_bounds__(256) void batch_topk(const unsigned long long* __restrict__ planeKeys,
                                                  float* __restrict__ dScore, int* __restrict__ dInd,
                                                  int* __restrict__ dCls) {
    __shared__ unsigned long long k2[NC * KK];
    __shared__ unsigned int sidx[NC * KK];

    const int b = blockIdx.x;
    const int tid = threadIdx.x;
    for (int j = tid; j < NC * KK; j += 256) {
        const unsigned long long pk = planeKeys[(b * NC + j / KK) * KK + (j % KK)];
        sidx[j] = 0xFFFFFFFFu - (unsigned int)(pk & 0xFFFFFFFFull);
        k2[j] = (pk & 0xFFFFFFFF00000000ull) | (unsigned long long)(0xFFFFFFFFu - (unsigned int)j);
    }
    __syncthreads();

    for (int idx = tid; idx < NC * KK; idx += 256) {
        const unsigned long long k = k2[idx];
        int r = 0;
        for (int j = 0; j < NC * KK; ++j) r += (k2[j] > k) ? 1 : 0;
        if (r < KK) {
            dScore[b * KK + r] = __uint_as_float((unsigned int)(k >> 32));
            dInd[b * KK + r] = (int)sidx[idx];
            dCls[b * KK + r] = idx / KK;
        }
    }
}

// Kernel 4: fused per-detection finalize. Lanes <26 issue the scattered reg
// loads early; all 64 lanes run the batch-global segment-max scan under that
// latency; lane 0 does the math + all writes (incl. valid flag).
__global__ __launch_bounds__(64) void finalize(const float* __restrict__ regs,
                                               const float* __restrict__ calib,
                                               const float* __restrict__ dScore,
                                               const int* __restrict__ dInd,
                                               const int* __restrict__ dCls,
                                               float* __restrict__ out) {
    __shared__ float s[26];
    const int i = blockIdx.x;
    const int lane = threadIdx.x;
    const int ind0 = dInd[i];
    const int ind = (ind0 >= 0 && ind0 < HW) ? ind0 : 0;  // OOB guard (degenerate planes)
    const int b = i / KK;

    if (lane < 26) {
        const int ch = (lane < 6) ? lane : lane + 16;  // 0-5, 22-24, 25-40, 41
        s[lane] = regs[(size_t)b * 46 * HW + (size_t)ch * HW + (size_t)ind];
    }

    // Batch-global segment-max over spatial index (reference segment_max semantics).
    float m = -INFINITY;
    for (int j = lane; j < NDET; j += 64) {
        if (dInd[j] == ind0 && dScore[j] >= 0.29f) {
            m = fmaxf(m, (float)dCls[j] * 10000.0f - (float)j);
        }
    }
#pragma unroll
    for (int sft = 32; sft > 0; sft >>= 1) m = fmaxf(m, __shfl_down(m, sft));
    __syncthreads();
    if (lane != 0) return;

    const int cls = dCls[i];
    const float score = dScore[i];
    const bool th = score >= 0.29f;
    const float key_i = th ? (float)cls * 10000.0f - (float)i : -INFINITY;
    const bool valid = th && (key_i == m);

    const float x = (float)(ind % Wd);
    const float y = (float)(ind / Wd);

    const float r0 = fmaxf(s[0], 0.0f), r1 = fmaxf(s[1], 0.0f);
    const float r2 = fmaxf(s[2], 0.0f), r3 = fmaxf(s[3], 0.0f);
    const float cx = x + s[4];
    const float cy = y + s[5];

    const float bx1 = fminf(fmaxf((cx - r0) * 4.0f, 0.0f), 1920.0f);
    const float by1 = fminf(fmaxf((cy - r1) * 4.0f, 0.0f), 1056.0f);
    const float bx2 = fminf(fmaxf((cx + r2) * 4.0f, 0.0f), 1920.0f);
    const float by2 = fminf(fmaxf((cy + r3) * 4.0f, 0.0f), 1056.0f);

    const float dim0 = expf(s[6]) * DIMM[cls][0];
    const float dim1 = expf(s[7]) * DIMM[cls][1];
    const float dim2 = expf(s[8]) * DIMM[cls][2];

    const float sig = 1.0f / (1.0f + expf(-s[25]));
    const float depth = fminf(fmaxf(1.0f / sig - 1.0f, 0.1f), 200.0f);

    const float fu = calib[0], cu = calib[2], fv = calib[5], cv = calib[6];
    const float bxo = calib[3] / -fu;
    const float byo = calib[7] / -fv;
    const float locx = (cx * 4.0f - cu) * depth / fu + bxo;
    const float locy = (cy * 4.0f - cv) * depth / fv + byo;

    float best = -INFINITY;
    int bidx = 0;
#pragma unroll
    for (int t = 0; t < 4; ++t) {
        const float l0 = s[9 + 2 * t], l1 = s[9 + 2 * t + 1];
        const float mm = fmaxf(l0, l1);
        const float p1 = expf(l1 - mm) / (expf(l0 - mm) + expf(l1 - mm));
        if (p1 > best) { best = p1; bidx = t; }
    }
    const float sel0 = s[17 + 2 * bidx], sel1 = s[17 + 2 * bidx + 1];
    float alpha = atanf(sel0 / sel1) + ACENT[bidx];
    const float ray = atanf(locx / depth);
    float roty = alpha + ray;
    if (roty > PI_F) roty -= TWO_PI_F;
    if (roty < -PI_F) roty += TWO_PI_F;
    if (alpha > PI_F) alpha -= TWO_PI_F;
    if (alpha < -PI_F) alpha += TWO_PI_F;

    float* o = out + (size_t)i * 14;
    o[0] = bx1; o[1] = by1; o[2] = bx2; o[3] = by2;
    o[4] = dim0; o[5] = dim1; o[6] = dim2;
    o[7] = depth;
    o[8] = locx; o[9] = locy; o[10] = depth;
    o[11] = roty; o[12] = alpha;
    o[13] = score;
    out[NDET * 14 + i] = valid ? 1.0f : 0.0f;
    out[NDET * 15 + i] = (float)cls;
}

extern "C" void kernel_launch(void* const* d_in, const int* in_sizes, int n_in,
                              void* d_out, int out_size, void* d_ws, size_t ws_size,
                              hipStream_t stream) {
    const float* cls = (const float*)d_in[0];
    const float* regs = (const float*)d_in[1];
    const float* calib = (const float*)d_in[2];
    float* out = (float*)d_out;
    char* ws = (char*)d_ws;

    // ws layout (every region fully rewritten each launch before it is read)
    int* slabCnt = (int*)ws;                                         // 144*8*4 B (pad 32K)
    unsigned long long* slabs = (unsigned long long*)(ws + 32768);   // 144*8*2048*8 = 18,874,368 B
    char* tail = ws + 32768 + 18874368;
    unsigned long long* planeKeys = (unsigned long long*)tail;       // 144*50*8 B
    float* dScore = (float*)(tail + 57600);
    int* dInd = (int*)(tail + 60800);
    int* dCls = (int*)(tail + 64000);

    hipLaunchKernelGGL(nms_stream, dim3(NCHUNK, NPLANE), dim3(128), 0, stream, cls, slabs, slabCnt);
    hipLaunchKernelGGL(plane_topk, dim3(NPLANE), dim3(256), 0, stream, slabs, slabCnt, planeKeys);
    hipLaunchKernelGGL(batch_topk, dim3(NB), dim3(256), 0, stream, planeKeys, dScore, dInd, dCls);
    hipLaunchKernelGGL(finalize, dim3(NDET), dim3(64), 0, stream, regs, calib, dScore, dInd, dCls, out);
}